// Round 13
// baseline (301.855 us; speedup 1.0000x reference)
//
#include <hip/hip_runtime.h>
#include <math.h>

namespace {

constexpr int D    = 49;
constexpr int H    = 8;
constexpr int L    = 4;
constexpr int HID  = 25;
constexpr int NCLS = 10;
constexpr int XS   = 68;    // LDS staging row stride (bf16 elems)
constexpr int WSM  = 4096;  // ushorts per padded 64x64 matrix in frag layout
// fold 1/(sqrt(49)+1e-6) * log2(e) into Wk so softmax uses exp2 directly
constexpr float SCLF  = 1.44269504088896f / (7.0f + 1e-6f);
constexpr float CLIP2 = 30.0f * 1.44269504088896f;  // clip bounds in log2 domain

typedef __attribute__((ext_vector_type(4))) short short4v;
typedef __attribute__((ext_vector_type(8))) short short8v;
typedef __attribute__((ext_vector_type(4))) float float4v;
typedef __attribute__((ext_vector_type(8))) __bf16 bf16x8;

__device__ __forceinline__ float4v mfma32(short8v a, short8v b, float4v c) {
  return __builtin_amdgcn_mfma_f32_16x16x32_bf16(a, b, c, 0, 0, 0);
}

__device__ __forceinline__ unsigned short f2bf(float x) {  // RNE
  unsigned u = __float_as_uint(x);
  return (unsigned short)((u + 0x7FFFu + ((u >> 16) & 1u)) >> 16);
}

__device__ __forceinline__ short8v cvt8(float4v lo, float4v hi) {
  bf16x8 b = {(__bf16)lo[0], (__bf16)lo[1], (__bf16)lo[2], (__bf16)lo[3],
              (__bf16)hi[0], (__bf16)hi[1], (__bf16)hi[2], (__bf16)hi[3]};
  return __builtin_bit_cast(short8v, b);
}

__device__ __forceinline__ float exp2_hw(float x) {  // x bounded by clip: safe
  float r;
  asm("v_exp_f32 %0, %1" : "=v"(r) : "v"(x));
  return r;
}

__device__ __forceinline__ float4v splat4(float x) {
  float4v v; v[0] = x; v[1] = x; v[2] = x; v[3] = x; return v;
}

__device__ __forceinline__ short8v wsld8(const unsigned short* __restrict__ w,
                                         int t, int nt, int lane) {
  return *reinterpret_cast<const short8v*>(w + ((t * 4 + nt) * 64 + lane) * 8);
}

// acc(cfrag of OUT^T) = W^T @ SRC   (all biases live inside W via ones-column)
__device__ __forceinline__ void mmT8(const unsigned short* __restrict__ w,
                                     const short8v (&src)[2][4],
                                     int lane, float4v (&acc)[4][4]) {
  #pragma unroll
  for (int mt = 0; mt < 4; ++mt)
    #pragma unroll
    for (int nt = 0; nt < 4; ++nt) acc[mt][nt] = splat4(0.0f);
  #pragma unroll
  for (int t = 0; t < 2; ++t) {
    short8v a[4];
    #pragma unroll
    for (int mt = 0; mt < 4; ++mt) a[mt] = wsld8(w, t, mt, lane);
    #pragma unroll
    for (int nt = 0; nt < 4; ++nt)
      #pragma unroll
      for (int mt = 0; mt < 4; ++mt)
        acc[mt][nt] = mfma32(a[mt], src[t][nt], acc[mt][nt]);
  }
}

// pack a 49x49 f32 LDS matrix (+bias row, +diag at [49][49]) into the padded
// 64x64 bf16 K=32-native frag layout at dst.
__device__ __forceinline__ void pack_from_lds(const float* __restrict__ M,
                                              const float* __restrict__ biasRow,
                                              float diag,
                                              unsigned short* __restrict__ dst,
                                              int tid) {
  const int lane = tid & 63;
  const int gg = (lane >> 4) & 3, cc = lane & 15;
  #pragma unroll
  for (int i = 0; i < 2; ++i) {
    const int p = ((tid >> 6) << 1) | i;  // 0..7
    const int tt = p >> 2, nt = p & 3;
    short8v v;
    #pragma unroll
    for (int j = 0; j < 8; ++j) {
      const int k = 32 * tt + ((j < 4) ? (4 * gg + j) : (16 + 4 * gg + j - 4));
      const int n = 16 * nt + cc;
      float f = 0.0f;
      if (k < D && n < D)        f = M[k * D + n];
      else if (k == D) {
        if (n < D)               f = biasRow[n];
        else if (n == D)         f = diag;
      }
      v[j] = (short)f2bf(f);
    }
    *reinterpret_cast<short8v*>(dst + ((tt * 4 + nt) * 64 + lane) * 8) = v;
  }
}

// ---- single-launch prep: compose + pack all 100 frag matrices ----
// block m: 0-31 Wq(+bq) | 32-63 Wk*SCLF(+bk*SCLF) | 64-95 Wfull=Wv@Wh@Wout
// (+bv@Wh@Wout row, diag 1/8) | 96-99 W12=W1@W2 (+b1@W2+b2+(sum_h bh@Wout)@W12,
// diag 1). All composition in f32 LDS; no global intermediates; one launch.
__global__ void __launch_bounds__(256)
prep_all(const float* __restrict__ Wq, const float* __restrict__ bq,
         const float* __restrict__ Wk, const float* __restrict__ bk,
         const float* __restrict__ Wv, const float* __restrict__ bv,
         const float* __restrict__ Wh, const float* __restrict__ bh,
         const float* __restrict__ Wout,
         const float* __restrict__ W1, const float* __restrict__ b1,
         const float* __restrict__ W2, const float* __restrict__ b2,
         unsigned short* __restrict__ ws) {
  __shared__ float MA[D * D], MB[D * D], MT[D * D];
  __shared__ float BR[64], CH[64];
  const int m = blockIdx.x;  // 0..99
  const int tid = threadIdx.x;
  unsigned short* dst = ws + (size_t)m * WSM;

  if (m < 64) {  // plain pack: Wq or scaled Wk
    const int hh = (m < 32) ? m : (m - 32);
    const float scl = (m < 32) ? 1.0f : SCLF;
    const float* src = ((m < 32) ? Wq : Wk) + (size_t)hh * D * D;
    const float* bsr = ((m < 32) ? bq : bk) + hh * D;
    for (int i = tid; i < D * D; i += 256) MT[i] = src[i] * scl;
    if (tid < D) BR[tid] = bsr[tid] * scl;
    __syncthreads();
    pack_from_lds(MT, BR, 0.0f, dst, tid);
    return;
  }

  if (m < 96) {  // head compose: Wfull = Wv @ (Wh @ Wout), bias = bv @ (Wh@Wout)
    const int lh = m - 64;
    const float* wh = Wh + (size_t)lh * D * D;
    const float* wo = Wout + (size_t)lh * D * D;
    const float* wv = Wv + (size_t)lh * D * D;
    for (int i = tid; i < D * D; i += 256) { MA[i] = wh[i]; MB[i] = wo[i]; }
    __syncthreads();
    for (int i = tid; i < D * D; i += 256) {  // MT = Wh @ Wout
      const int r = i / D, c = i - r * D;
      float s = 0.0f;
      #pragma unroll 1
      for (int k = 0; k < D; ++k) s = fmaf(MA[r * D + k], MB[k * D + c], s);
      MT[i] = s;
    }
    __syncthreads();
    for (int i = tid; i < D * D; i += 256) MA[i] = wv[i];
    if (tid < D) {  // bias row = bv @ MT
      float s = 0.0f;
      #pragma unroll 1
      for (int k = 0; k < D; ++k) s = fmaf(bv[lh * D + k], MT[k * D + tid], s);
      BR[tid] = s;
    }
    __syncthreads();
    for (int i = tid; i < D * D; i += 256) {  // MB = Wv @ MT
      const int r = i / D, c = i - r * D;
      float s = 0.0f;
      #pragma unroll 1
      for (int k = 0; k < D; ++k) s = fmaf(MA[r * D + k], MT[k * D + c], s);
      MB[i] = s;
    }
    __syncthreads();
    pack_from_lds(MB, BR, 0.125f, dst, tid);
    return;
  }

  // layer compose: W12 = W1 @ W2; bias = b1@W2 + b2 + (sum_h bh@Wout)@W12
  const int l = m - 96;
  for (int i = tid; i < D * D; i += 256) {
    MA[i] = W1[(size_t)l * D * D + i];
    MB[i] = W2[(size_t)l * D * D + i];
  }
  if (tid < D) {  // CH = sum_h bh @ Wout (cheap: 8*49 FMAs per output elem)
    float s = 0.0f;
    #pragma unroll 1
    for (int h = 0; h < H; ++h) {
      const int lh = l * H + h;
      #pragma unroll 1
      for (int k = 0; k < D; ++k)
        s = fmaf(bh[lh * D + k], Wout[(size_t)lh * D * D + k * D + tid], s);
    }
    CH[tid] = s;
  }
  __syncthreads();
  for (int i = tid; i < D * D; i += 256) {  // MT = W1 @ W2
    const int r = i / D, c = i - r * D;
    float s = 0.0f;
    #pragma unroll 1
    for (int k = 0; k < D; ++k) s = fmaf(MA[r * D + k], MB[k * D + c], s);
    MT[i] = s;
  }
  __syncthreads();
  if (tid < D) {  // bias row
    float s = b2[l * D + tid];
    #pragma unroll 1
    for (int k = 0; k < D; ++k) {
      s = fmaf(b1[l * D + k], MB[k * D + tid], s);
      s = fmaf(CH[k], MT[k * D + tid], s);
    }
    BR[tid] = s;
  }
  __syncthreads();
  pack_from_lds(MT, BR, 1.0f, dst, tid);
}

__global__ void __launch_bounds__(64, 2)
encoder_kernel(const float* __restrict__ emb, const int* __restrict__ labels,
               const unsigned short* __restrict__ ws,
               const float* __restrict__ Wc1, const float* __restrict__ bc1,
               const float* __restrict__ Wc2, const float* __restrict__ bc2,
               float* __restrict__ ws_loss, float* __restrict__ ws_corr) {
  __shared__ unsigned short X[64 * XS];  // embedding staging only
  __shared__ float CLS[128];

  const int b = blockIdx.x;
  const int lane = threadIdx.x;          // one wave per block
  const int g = lane >> 4, c = lane & 15;

  // ---- stage embedding (64x64 bf16; col 49 = ones-column, rest pad 0) ----
  for (int idx = lane; idx < 64 * 64; idx += 64) {
    const int r = idx >> 6, cc = idx & 63;
    float v = 0.0f;
    if (cc == D) v = 1.0f;
    else if (r < D && cc < D) v = emb[(size_t)b * (D * D) + r * D + cc];
    X[r * XS + cc] = f2bf(v);
  }
  __syncthreads();

  short8v xf8[2][4];  // operand frag of X (contraction over d)
  #pragma unroll
  for (int t = 0; t < 2; ++t)
    #pragma unroll
    for (int nt = 0; nt < 4; ++nt) {
      const int base = (16 * nt + c) * XS + 32 * t + 4 * g;
      short4v lo = *reinterpret_cast<const short4v*>(&X[base]);
      short4v hi = *reinterpret_cast<const short4v*>(&X[base + 16]);
      xf8[t][nt] = __builtin_shufflevector(lo, hi, 0, 1, 2, 3, 4, 5, 6, 7);
    }

  float4v xacc[4][4];  // cfrag(x^T)

  #pragma unroll 1
  for (int l = 0; l < L; ++l) {
    float4v od[4][4];  // cfrag(od^T) f32 accumulator across heads
    #pragma unroll
    for (int mt = 0; mt < 4; ++mt)
      #pragma unroll
      for (int nt = 0; nt < 4; ++nt) od[mt][nt] = splat4(0.0f);

    // unroll 2: consecutive heads are independent until the od accumulate.
    #pragma unroll 2
    for (int h = 0; h < H; ++h) {
      const int lh = l * H + h;
      const unsigned short* wq = ws + (size_t)(0  + lh) * WSM;
      const unsigned short* wk = ws + (size_t)(32 + lh) * WSM;
      const unsigned short* wf = ws + (size_t)(64 + lh) * WSM;

      // ---- K^T (pre-scaled, log2 domain) and Q^T ----
      short8v kf8[2][4], qf8[2][4];
      {
        float4v ka[4][4];
        mmT8(wk, xf8, lane, ka);
        #pragma unroll
        for (int t = 0; t < 2; ++t)
          #pragma unroll
          for (int nt = 0; nt < 4; ++nt)
            kf8[t][nt] = cvt8(ka[2 * t][nt], ka[2 * t + 1][nt]);
      }
      {
        float4v qa[4][4];
        mmT8(wq, xf8, lane, qa);
        #pragma unroll
        for (int t = 0; t < 2; ++t)
          #pragma unroll
          for (int nt = 0; nt < 4; ++nt)
            qf8[t][nt] = cvt8(qa[2 * t][nt], qa[2 * t + 1][nt]);
      }

      // ---- S^T = K @ Q^T (log2 domain) ----
      float4v s[4][4];
      #pragma unroll
      for (int mt = 0; mt < 4; ++mt)
        #pragma unroll
        for (int nt = 0; nt < 4; ++nt) s[mt][nt] = splat4(0.0f);
      #pragma unroll
      for (int t = 0; t < 2; ++t)
        #pragma unroll
        for (int nt = 0; nt < 4; ++nt)
          #pragma unroll
          for (int mt = 0; mt < 4; ++mt)
            s[mt][nt] = mfma32(kf8[t][mt], qf8[t][nt], s[mt][nt]);

      // ---- U = X @ Wfull' (rows = patch, cols = o; col 49 = 1/8) ----
      short8v uf8[2][4];
      {
        float4v ua[4][4];
        #pragma unroll
        for (int nt = 0; nt < 4; ++nt)
          #pragma unroll
          for (int mt = 0; mt < 4; ++mt) ua[mt][nt] = splat4(0.0f);
        #pragma unroll
        for (int t = 0; t < 2; ++t) {
          short8v wff[4];
          #pragma unroll
          for (int nt = 0; nt < 4; ++nt) wff[nt] = wsld8(wf, t, nt, lane);
          #pragma unroll
          for (int nt = 0; nt < 4; ++nt)
            #pragma unroll
            for (int mt = 0; mt < 4; ++mt)
              ua[mt][nt] = mfma32(xf8[t][mt], wff[nt], ua[mt][nt]);
        }
        #pragma unroll
        for (int t = 0; t < 2; ++t)
          #pragma unroll
          for (int nt = 0; nt < 4; ++nt)
            uf8[t][nt] = cvt8(ua[2 * t][nt], ua[2 * t + 1][nt]);
      }

      // ---- max-free softmax: clip bounds exp2; pad keys masked at compile
      //      time (key j = 16mt+4g+r: mt==3,r>0 always pad; r==0 needs g==0) ----
      short8v pf8[2][4];
      #pragma unroll
      for (int mt = 0; mt < 4; ++mt)
        #pragma unroll
        for (int nt = 0; nt < 4; ++nt)
          #pragma unroll
          for (int r = 0; r < 4; ++r) {
            if (mt == 3 && r > 0) { s[mt][nt][r] = 0.0f; continue; }
            const float sv = fminf(fmaxf(s[mt][nt][r], -CLIP2), CLIP2);
            float p = exp2_hw(sv);
            if (mt == 3) p = (g == 0) ? p : 0.0f;
            s[mt][nt][r] = p;
          }
      #pragma unroll
      for (int t = 0; t < 2; ++t)
        #pragma unroll
        for (int nt = 0; nt < 4; ++nt)
          pf8[t][nt] = cvt8(s[2 * t][nt], s[2 * t + 1][nt]);

      // ---- ca = U^T-contract P~: od-contribution (unnormalized);
      //      row 49 = den/8 (U ones-col = 1/8); od += ca * (0.125/ca49) ----
      float4v ca[4][4];
      #pragma unroll
      for (int mt = 0; mt < 4; ++mt)
        #pragma unroll
        for (int nt = 0; nt < 4; ++nt) ca[mt][nt] = splat4(0.0f);
      #pragma unroll
      for (int t = 0; t < 2; ++t)
        #pragma unroll
        for (int nt = 0; nt < 4; ++nt)
          #pragma unroll
          for (int mt = 0; mt < 4; ++mt)
            ca[mt][nt] = mfma32(uf8[t][mt], pf8[t][nt], ca[mt][nt]);
      #pragma unroll
      for (int nt = 0; nt < 4; ++nt) {
        // row 49 = (mt=3, g=0, reg r=1); lane c holds col q=16nt+c at g=0
        const float inv = 0.125f / __shfl(ca[3][nt][1], c);
        const float4v iv = splat4(inv);
        #pragma unroll
        for (int mt = 0; mt < 4; ++mt)
          od[mt][nt] += ca[mt][nt] * iv;
      }
    }  // heads

    // ---- fused MLP: x^T = W12'^T @ od^T (bias+head-bias in row 49) ----
    short8v of8[2][4];
    #pragma unroll
    for (int t = 0; t < 2; ++t)
      #pragma unroll
      for (int nt = 0; nt < 4; ++nt)
        of8[t][nt] = cvt8(od[2 * t][nt], od[2 * t + 1][nt]);
    mmT8(ws + (size_t)(96 + l) * WSM, of8, lane, xacc);

    if (l < L - 1) {
      #pragma unroll
      for (int t = 0; t < 2; ++t)
        #pragma unroll
        for (int nt = 0; nt < 4; ++nt)
          xf8[t][nt] = cvt8(xacc[2 * t][nt], xacc[2 * t + 1][nt]);
    }
  }  // layers

  // ---- pooled[d] = mean over patch cols < 49 of x^T ----
  #pragma unroll
  for (int mt = 0; mt < 4; ++mt) {
    #pragma unroll
    for (int r = 0; r < 4; ++r) {
      float sv = xacc[mt][0][r] + xacc[mt][1][r] + xacc[mt][2][r];
      if (c == 0) sv += xacc[mt][3][r];  // patch 48; 49..63 pad
      sv += __shfl_xor(sv, 1);
      sv += __shfl_xor(sv, 2);
      sv += __shfl_xor(sv, 4);
      sv += __shfl_xor(sv, 8);
      if (c == 0) CLS[16 * mt + 4 * g + r] = sv * (1.0f / 49.0f);
    }
  }
  __syncthreads();

  // ---- classifier head (f32 scalar path) ----
  if (lane < HID) {
    float acc = bc1[lane];
    #pragma unroll 1
    for (int d = 0; d < D; ++d) acc = fmaf(CLS[d], Wc1[d * HID + lane], acc);
    CLS[64 + lane] = acc;
  }
  __syncthreads();
  if (lane < NCLS) {
    float acc = bc2[lane];
    #pragma unroll 1
    for (int j = 0; j < HID; ++j) acc = fmaf(CLS[64 + j], Wc2[j * NCLS + lane], acc);
    CLS[96 + lane] = acc;
  }
  __syncthreads();
  if (lane == 0) {
    float mx = CLS[96];
    int am = 0;
    #pragma unroll 1
    for (int cc = 1; cc < NCLS; ++cc) {
      const float v = CLS[96 + cc];
      if (v > mx) { mx = v; am = cc; }  // strict '>' == first max (jnp.argmax)
    }
    float se = 0.0f;
    #pragma unroll 1
    for (int cc = 0; cc < NCLS; ++cc) se += expf(CLS[96 + cc] - mx);
    const float lse = mx + logf(se);
    const int lbl = labels[b];
    ws_loss[b] = lse - CLS[96 + lbl];
    ws_corr[b] = (am == lbl) ? 1.0f : 0.0f;
  }
}

__global__ void __launch_bounds__(256)
reduce_kernel(const float* __restrict__ wsl, const float* __restrict__ wsc,
              float* __restrict__ out, int n) {
  __shared__ float sl[256];
  __shared__ float sc[256];
  const int t = threadIdx.x;
  float a = 0.0f, cc = 0.0f;
  for (int idx = t; idx < n; idx += 256) { a += wsl[idx]; cc += wsc[idx]; }
  sl[t] = a; sc[t] = cc;
  __syncthreads();
  for (int s = 128; s > 0; s >>= 1) {
    if (t < s) { sl[t] += sl[t + s]; sc[t] += sc[t + s]; }
    __syncthreads();
  }
  if (t == 0) {
    out[0] = sl[0] / (float)n;
    out[1] = sc[0] / (float)n;
  }
}

}  // namespace

extern "C" void kernel_launch(void* const* d_in, const int* in_sizes, int n_in,
                              void* d_out, int out_size, void* d_ws, size_t ws_size,
                              hipStream_t stream) {
  const float* emb    = (const float*)d_in[0];
  const int*   labels = (const int*)d_in[1];
  const float* Wq   = (const float*)d_in[2];
  const float* bq   = (const float*)d_in[3];
  const float* Wk   = (const float*)d_in[4];
  const float* bk   = (const float*)d_in[5];
  const float* Wv   = (const float*)d_in[6];
  const float* bv   = (const float*)d_in[7];
  const float* Wh   = (const float*)d_in[8];
  const float* bh   = (const float*)d_in[9];
  const float* Wout = (const float*)d_in[10];
  const float* W1   = (const float*)d_in[11];
  const float* b1   = (const float*)d_in[12];
  const float* W2   = (const float*)d_in[13];
  const float* b2   = (const float*)d_in[14];
  const float* Wc1  = (const float*)d_in[15];
  const float* bc1  = (const float*)d_in[16];
  const float* Wc2  = (const float*)d_in[17];
  const float* bc2  = (const float*)d_in[18];

  const int B = in_sizes[1];  // 2048
  const size_t fragB = (size_t)100 * WSM * sizeof(unsigned short);
  const size_t need = fragB + (size_t)2 * B * sizeof(float);
  if (ws_size < need) return;

  unsigned short* wsb = (unsigned short*)d_ws;
  float* wsf = (float*)((char*)d_ws + fragB);
  float* out = (float*)d_out;

  prep_all<<<100, 256, 0, stream>>>(Wq, bq, Wk, bk, Wv, bv, Wh, bh, Wout,
                                    W1, b1, W2, b2, wsb);
  encoder_kernel<<<B, 64, 0, stream>>>(emb, labels, wsb, Wc1, bc1, Wc2, bc2,
                                       wsf, wsf + B);
  reduce_kernel<<<1, 256, 0, stream>>>(wsf, wsf + B, out, B);
}

// Round 14
// 170.033 us; speedup vs baseline: 1.7753x; 1.7753x over previous
//
#include <hip/hip_runtime.h>
#include <math.h>

namespace {

constexpr int D    = 49;
constexpr int H    = 8;
constexpr int L    = 4;
constexpr int HID  = 25;
constexpr int NCLS = 10;
constexpr int XS   = 68;    // LDS staging row stride (bf16 elems)
constexpr int WSM  = 4096;  // ushorts per padded 64x64 matrix in frag layout
// fold 1/(sqrt(49)+1e-6) * log2(e) into Wk so softmax uses exp2 directly
constexpr float SCLF  = 1.44269504088896f / (7.0f + 1e-6f);
constexpr float CLIP2 = 30.0f * 1.44269504088896f;  // clip bounds in log2 domain

typedef __attribute__((ext_vector_type(4))) short short4v;
typedef __attribute__((ext_vector_type(8))) short short8v;
typedef __attribute__((ext_vector_type(4))) float float4v;
typedef __attribute__((ext_vector_type(8))) __bf16 bf16x8;

__device__ __forceinline__ float4v mfma32(short8v a, short8v b, float4v c) {
  return __builtin_amdgcn_mfma_f32_16x16x32_bf16(a, b, c, 0, 0, 0);
}

__device__ __forceinline__ unsigned short f2bf(float x) {  // RNE
  unsigned u = __float_as_uint(x);
  return (unsigned short)((u + 0x7FFFu + ((u >> 16) & 1u)) >> 16);
}

__device__ __forceinline__ short8v cvt8(float4v lo, float4v hi) {
  bf16x8 b = {(__bf16)lo[0], (__bf16)lo[1], (__bf16)lo[2], (__bf16)lo[3],
              (__bf16)hi[0], (__bf16)hi[1], (__bf16)hi[2], (__bf16)hi[3]};
  return __builtin_bit_cast(short8v, b);
}

__device__ __forceinline__ float exp2_hw(float x) {  // x bounded by clip: safe
  float r;
  asm("v_exp_f32 %0, %1" : "=v"(r) : "v"(x));
  return r;
}

__device__ __forceinline__ float4v splat4(float x) {
  float4v v; v[0] = x; v[1] = x; v[2] = x; v[3] = x; return v;
}

__device__ __forceinline__ short8v wsld8(const unsigned short* __restrict__ w,
                                         int t, int nt, int lane) {
  return *reinterpret_cast<const short8v*>(w + ((t * 4 + nt) * 64 + lane) * 8);
}

// acc(cfrag of OUT^T) = W^T @ SRC   (all biases live inside W via ones-column)
__device__ __forceinline__ void mmT8(const unsigned short* __restrict__ w,
                                     const short8v (&src)[2][4],
                                     int lane, float4v (&acc)[4][4]) {
  #pragma unroll
  for (int mt = 0; mt < 4; ++mt)
    #pragma unroll
    for (int nt = 0; nt < 4; ++nt) acc[mt][nt] = splat4(0.0f);
  #pragma unroll
  for (int t = 0; t < 2; ++t) {
    short8v a[4];
    #pragma unroll
    for (int mt = 0; mt < 4; ++mt) a[mt] = wsld8(w, t, mt, lane);
    #pragma unroll
    for (int nt = 0; nt < 4; ++nt)
      #pragma unroll
      for (int mt = 0; mt < 4; ++mt)
        acc[mt][nt] = mfma32(a[mt], src[t][nt], acc[mt][nt]);
  }
}

// pack a 49x49 f32 LDS matrix (+bias row, +diag at [49][49]) into the padded
// 64x64 bf16 K=32-native frag layout at dst.
__device__ __forceinline__ void pack_from_lds(const float* __restrict__ M,
                                              const float* __restrict__ biasRow,
                                              float diag,
                                              unsigned short* __restrict__ dst,
                                              int tid) {
  const int lane = tid & 63;
  const int gg = (lane >> 4) & 3, cc = lane & 15;
  #pragma unroll
  for (int i = 0; i < 2; ++i) {
    const int p = ((tid >> 6) << 1) | i;  // 0..7
    const int tt = p >> 2, nt = p & 3;
    short8v v;
    #pragma unroll
    for (int j = 0; j < 8; ++j) {
      const int k = 32 * tt + ((j < 4) ? (4 * gg + j) : (16 + 4 * gg + j - 4));
      const int n = 16 * nt + cc;
      float f = 0.0f;
      if (k < D && n < D)        f = M[k * D + n];
      else if (k == D) {
        if (n < D)               f = biasRow[n];
        else if (n == D)         f = diag;
      }
      v[j] = (short)f2bf(f);
    }
    *reinterpret_cast<short8v*>(dst + ((tt * 4 + nt) * 64 + lane) * 8) = v;
  }
}

// 49x49 @ 49x49 in LDS, output to LDS. k-loop fully unrolled: 98 independent
// LDS loads issue together; FMA chain ~200cyc/output (ILP across outputs).
__device__ __forceinline__ void lds_mm(const float* __restrict__ A49,
                                       const float* __restrict__ B49,
                                       float* __restrict__ OUT, int tid) {
  for (int i = tid; i < D * D; i += 256) {
    const int r = i / D, c = i - r * D;
    float s = 0.0f;
    #pragma unroll
    for (int k = 0; k < D; ++k) s = fmaf(A49[r * D + k], B49[k * D + c], s);
    OUT[i] = s;
  }
}

// ---- single-launch prep: compose + pack all 100 frag matrices ----
// block m: 0-31 Wq(+bq) | 32-63 Wk*SCLF(+bk*SCLF) | 64-95 Wfull=Wv@Wh@Wout
// (+bv@Wh@Wout row, diag 1/8) | 96-99 W12=W1@W2 (+b1@W2+b2+(sum_h bh@Wout)@W12,
// diag 1). All composition in f32 LDS; fully-unrolled k-loops for ILP.
__global__ void __launch_bounds__(256)
prep_all(const float* __restrict__ Wq, const float* __restrict__ bq,
         const float* __restrict__ Wk, const float* __restrict__ bk,
         const float* __restrict__ Wv, const float* __restrict__ bv,
         const float* __restrict__ Wh, const float* __restrict__ bh,
         const float* __restrict__ Wout,
         const float* __restrict__ W1, const float* __restrict__ b1,
         const float* __restrict__ W2, const float* __restrict__ b2,
         unsigned short* __restrict__ ws) {
  __shared__ float MA[D * D], MB[D * D], MT[D * D];
  __shared__ float BR[64], CH[64], BH[8 * 64];
  const int m = blockIdx.x;  // 0..99
  const int tid = threadIdx.x;
  unsigned short* dst = ws + (size_t)m * WSM;

  if (m < 64) {  // plain pack: Wq or scaled Wk
    const int hh = (m < 32) ? m : (m - 32);
    const float scl = (m < 32) ? 1.0f : SCLF;
    const float* src = ((m < 32) ? Wq : Wk) + (size_t)hh * D * D;
    const float* bsr = ((m < 32) ? bq : bk) + hh * D;
    for (int i = tid; i < D * D; i += 256) MT[i] = src[i] * scl;
    if (tid < D) BR[tid] = bsr[tid] * scl;
    __syncthreads();
    pack_from_lds(MT, BR, 0.0f, dst, tid);
    return;
  }

  if (m < 96) {  // head compose: Wfull = Wv @ (Wh @ Wout), bias = bv @ (Wh@Wout)
    const int lh = m - 64;
    const float* wh = Wh + (size_t)lh * D * D;
    const float* wo = Wout + (size_t)lh * D * D;
    const float* wv = Wv + (size_t)lh * D * D;
    for (int i = tid; i < D * D; i += 256) { MA[i] = wh[i]; MB[i] = wo[i]; }
    __syncthreads();
    lds_mm(MA, MB, MT, tid);  // MT = Wh @ Wout
    __syncthreads();
    for (int i = tid; i < D * D; i += 256) MA[i] = wv[i];
    if (tid < D) {  // bias row = bv @ MT
      float s = 0.0f;
      #pragma unroll
      for (int k = 0; k < D; ++k) s = fmaf(bv[lh * D + k], MT[k * D + tid], s);
      BR[tid] = s;
    }
    __syncthreads();
    lds_mm(MA, MT, MB, tid);  // MB = Wv @ MT
    __syncthreads();
    pack_from_lds(MB, BR, 0.125f, dst, tid);
    return;
  }

  // layer compose: W12 = W1 @ W2; bias = b1@W2 + b2 + (sum_h bh@Wout)@W12
  const int l = m - 96;
  for (int i = tid; i < D * D; i += 256) {
    MA[i] = W1[(size_t)l * D * D + i];
    MB[i] = W2[(size_t)l * D * D + i];
  }
  for (int i = tid; i < H * D; i += 256)  // stage bh for this layer
    BH[(i / D) * 64 + (i % D)] = bh[(l * H + (i / D)) * D + (i % D)];
  __syncthreads();
  if (tid < D) {  // CH[c] = sum_h (bh_h @ Wout_h)[c]; unrolled loads pipeline
    float s = 0.0f;
    #pragma unroll
    for (int h = 0; h < H; ++h) {
      const size_t base = (size_t)(l * H + h) * D * D;
      #pragma unroll
      for (int k = 0; k < D; ++k)
        s = fmaf(BH[h * 64 + k], Wout[base + k * D + tid], s);
    }
    CH[tid] = s;
  }
  __syncthreads();
  lds_mm(MA, MB, MT, tid);  // MT = W1 @ W2
  __syncthreads();
  if (tid < D) {  // bias row
    float s = b2[l * D + tid];
    #pragma unroll
    for (int k = 0; k < D; ++k) {
      s = fmaf(b1[l * D + k], MB[k * D + tid], s);
      s = fmaf(CH[k], MT[k * D + tid], s);
    }
    BR[tid] = s;
  }
  __syncthreads();
  pack_from_lds(MT, BR, 1.0f, dst, tid);
}

__global__ void __launch_bounds__(64, 2)
encoder_kernel(const float* __restrict__ emb, const int* __restrict__ labels,
               const unsigned short* __restrict__ ws,
               const float* __restrict__ Wc1, const float* __restrict__ bc1,
               const float* __restrict__ Wc2, const float* __restrict__ bc2,
               float* __restrict__ ws_loss, float* __restrict__ ws_corr) {
  __shared__ unsigned short X[64 * XS];  // embedding staging only
  __shared__ float CLS[128];

  const int b = blockIdx.x;
  const int lane = threadIdx.x;          // one wave per block
  const int g = lane >> 4, c = lane & 15;

  // ---- stage embedding (64x64 bf16; col 49 = ones-column, rest pad 0) ----
  for (int idx = lane; idx < 64 * 64; idx += 64) {
    const int r = idx >> 6, cc = idx & 63;
    float v = 0.0f;
    if (cc == D) v = 1.0f;
    else if (r < D && cc < D) v = emb[(size_t)b * (D * D) + r * D + cc];
    X[r * XS + cc] = f2bf(v);
  }
  __syncthreads();

  short8v xf8[2][4];  // operand frag of X (contraction over d)
  #pragma unroll
  for (int t = 0; t < 2; ++t)
    #pragma unroll
    for (int nt = 0; nt < 4; ++nt) {
      const int base = (16 * nt + c) * XS + 32 * t + 4 * g;
      short4v lo = *reinterpret_cast<const short4v*>(&X[base]);
      short4v hi = *reinterpret_cast<const short4v*>(&X[base + 16]);
      xf8[t][nt] = __builtin_shufflevector(lo, hi, 0, 1, 2, 3, 4, 5, 6, 7);
    }

  float4v xacc[4][4];  // cfrag(x^T)

  #pragma unroll 1
  for (int l = 0; l < L; ++l) {
    float4v od[4][4];  // cfrag(od^T) f32 accumulator across heads
    #pragma unroll
    for (int mt = 0; mt < 4; ++mt)
      #pragma unroll
      for (int nt = 0; nt < 4; ++nt) od[mt][nt] = splat4(0.0f);

    // unroll 2: consecutive heads are independent until the od accumulate.
    #pragma unroll 2
    for (int h = 0; h < H; ++h) {
      const int lh = l * H + h;
      const unsigned short* wq = ws + (size_t)(0  + lh) * WSM;
      const unsigned short* wk = ws + (size_t)(32 + lh) * WSM;
      const unsigned short* wf = ws + (size_t)(64 + lh) * WSM;

      // ---- K^T (pre-scaled, log2 domain) and Q^T ----
      short8v kf8[2][4], qf8[2][4];
      {
        float4v ka[4][4];
        mmT8(wk, xf8, lane, ka);
        #pragma unroll
        for (int t = 0; t < 2; ++t)
          #pragma unroll
          for (int nt = 0; nt < 4; ++nt)
            kf8[t][nt] = cvt8(ka[2 * t][nt], ka[2 * t + 1][nt]);
      }
      {
        float4v qa[4][4];
        mmT8(wq, xf8, lane, qa);
        #pragma unroll
        for (int t = 0; t < 2; ++t)
          #pragma unroll
          for (int nt = 0; nt < 4; ++nt)
            qf8[t][nt] = cvt8(qa[2 * t][nt], qa[2 * t + 1][nt]);
      }

      // ---- U = X @ Wfull' (rows = patch, cols = o; col 49 = 1/8) ----
      short8v uf8[2][4];
      {
        float4v ua[4][4];
        #pragma unroll
        for (int nt = 0; nt < 4; ++nt)
          #pragma unroll
          for (int mt = 0; mt < 4; ++mt) ua[mt][nt] = splat4(0.0f);
        #pragma unroll
        for (int t = 0; t < 2; ++t) {
          short8v wff[4];
          #pragma unroll
          for (int nt = 0; nt < 4; ++nt) wff[nt] = wsld8(wf, t, nt, lane);
          #pragma unroll
          for (int nt = 0; nt < 4; ++nt)
            #pragma unroll
            for (int mt = 0; mt < 4; ++mt)
              ua[mt][nt] = mfma32(xf8[t][mt], wff[nt], ua[mt][nt]);
        }
        #pragma unroll
        for (int t = 0; t < 2; ++t)
          #pragma unroll
          for (int nt = 0; nt < 4; ++nt)
            uf8[t][nt] = cvt8(ua[2 * t][nt], ua[2 * t + 1][nt]);
      }

      // ---- per query-column-tile nt: scores -> softmax -> PU -> od.
      //      Transients per nt: sc[4]+pf(2)+cc[4] ~= 40 regs (vs 160 for the
      //      whole-tile version) -> no spill, chains still overlap across nt.
      #pragma unroll
      for (int nt = 0; nt < 4; ++nt) {
        float4v sc[4];
        #pragma unroll
        for (int mt = 0; mt < 4; ++mt) sc[mt] = splat4(0.0f);
        #pragma unroll
        for (int t = 0; t < 2; ++t)
          #pragma unroll
          for (int mt = 0; mt < 4; ++mt)
            sc[mt] = mfma32(kf8[t][mt], qf8[t][nt], sc[mt]);

        // max-free softmax (log2 domain); compile-time pad mask:
        // key j = 16mt+4g+r: mt==3,r>0 always pad; mt==3,r==0 needs g==0.
        #pragma unroll
        for (int mt = 0; mt < 4; ++mt)
          #pragma unroll
          for (int r = 0; r < 4; ++r) {
            if (mt == 3 && r > 0) { sc[mt][r] = 0.0f; continue; }
            const float sv = fminf(fmaxf(sc[mt][r], -CLIP2), CLIP2);
            float p = exp2_hw(sv);
            if (mt == 3) p = (g == 0) ? p : 0.0f;
            sc[mt][r] = p;
          }
        const short8v pf0 = cvt8(sc[0], sc[1]);
        const short8v pf1 = cvt8(sc[2], sc[3]);

        float4v cc[4];
        #pragma unroll
        for (int mt = 0; mt < 4; ++mt) cc[mt] = splat4(0.0f);
        #pragma unroll
        for (int mt = 0; mt < 4; ++mt) {
          cc[mt] = mfma32(uf8[0][mt], pf0, cc[mt]);
          cc[mt] = mfma32(uf8[1][mt], pf1, cc[mt]);
        }
        // row 49 = (mt=3, g=0, reg r=1) holds den/8; lane c reads col q=16nt+c
        const float inv = 0.125f / __shfl(cc[3][1], c);
        const float4v iv = splat4(inv);
        #pragma unroll
        for (int mt = 0; mt < 4; ++mt)
          od[mt][nt] += cc[mt] * iv;
      }
    }  // heads

    // ---- fused MLP: x^T = W12'^T @ od^T (bias+head-bias in row 49) ----
    short8v of8[2][4];
    #pragma unroll
    for (int t = 0; t < 2; ++t)
      #pragma unroll
      for (int nt = 0; nt < 4; ++nt)
        of8[t][nt] = cvt8(od[2 * t][nt], od[2 * t + 1][nt]);
    mmT8(ws + (size_t)(96 + l) * WSM, of8, lane, xacc);

    if (l < L - 1) {
      #pragma unroll
      for (int t = 0; t < 2; ++t)
        #pragma unroll
        for (int nt = 0; nt < 4; ++nt)
          xf8[t][nt] = cvt8(xacc[2 * t][nt], xacc[2 * t + 1][nt]);
    }
  }  // layers

  // ---- pooled[d] = mean over patch cols < 49 of x^T ----
  #pragma unroll
  for (int mt = 0; mt < 4; ++mt) {
    #pragma unroll
    for (int r = 0; r < 4; ++r) {
      float sv = xacc[mt][0][r] + xacc[mt][1][r] + xacc[mt][2][r];
      if (c == 0) sv += xacc[mt][3][r];  // patch 48; 49..63 pad
      sv += __shfl_xor(sv, 1);
      sv += __shfl_xor(sv, 2);
      sv += __shfl_xor(sv, 4);
      sv += __shfl_xor(sv, 8);
      if (c == 0) CLS[16 * mt + 4 * g + r] = sv * (1.0f / 49.0f);
    }
  }
  __syncthreads();

  // ---- classifier head (f32 scalar path) ----
  if (lane < HID) {
    float acc = bc1[lane];
    #pragma unroll
    for (int d = 0; d < D; ++d) acc = fmaf(CLS[d], Wc1[d * HID + lane], acc);
    CLS[64 + lane] = acc;
  }
  __syncthreads();
  if (lane < NCLS) {
    float acc = bc2[lane];
    #pragma unroll
    for (int j = 0; j < HID; ++j) acc = fmaf(CLS[64 + j], Wc2[j * NCLS + lane], acc);
    CLS[96 + lane] = acc;
  }
  __syncthreads();
  if (lane == 0) {
    float mx = CLS[96];
    int am = 0;
    #pragma unroll 1
    for (int cc2 = 1; cc2 < NCLS; ++cc2) {
      const float v = CLS[96 + cc2];
      if (v > mx) { mx = v; am = cc2; }  // strict '>' == first max (jnp.argmax)
    }
    float se = 0.0f;
    #pragma unroll 1
    for (int cc2 = 0; cc2 < NCLS; ++cc2) se += expf(CLS[96 + cc2] - mx);
    const float lse = mx + logf(se);
    const int lbl = labels[b];
    ws_loss[b] = lse - CLS[96 + lbl];
    ws_corr[b] = (am == lbl) ? 1.0f : 0.0f;
  }
}

__global__ void __launch_bounds__(256)
reduce_kernel(const float* __restrict__ wsl, const float* __restrict__ wsc,
              float* __restrict__ out, int n) {
  __shared__ float sl[256];
  __shared__ float sc[256];
  const int t = threadIdx.x;
  float a = 0.0f, cc = 0.0f;
  for (int idx = t; idx < n; idx += 256) { a += wsl[idx]; cc += wsc[idx]; }
  sl[t] = a; sc[t] = cc;
  __syncthreads();
  for (int s = 128; s > 0; s >>= 1) {
    if (t < s) { sl[t] += sl[t + s]; sc[t] += sc[t + s]; }
    __syncthreads();
  }
  if (t == 0) {
    out[0] = sl[0] / (float)n;
    out[1] = sc[0] / (float)n;
  }
}

}  // namespace

extern "C" void kernel_launch(void* const* d_in, const int* in_sizes, int n_in,
                              void* d_out, int out_size, void* d_ws, size_t ws_size,
                              hipStream_t stream) {
  const float* emb    = (const float*)d_in[0];
  const int*   labels = (const int*)d_in[1];
  const float* Wq   = (const float*)d_in[2];
  const float* bq   = (const float*)d_in[3];
  const float* Wk   = (const float*)d_in[4];
  const float* bk   = (const float*)d_in[5];
  const float* Wv   = (const float*)d_in[6];
  const float* bv   = (const float*)d_in[7];
  const float* Wh   = (const float*)d_in[8];
  const float* bh   = (const float*)d_in[9];
  const float* Wout = (const float*)d_in[10];
  const float* W1   = (const float*)d_in[11];
  const float* b1   = (const float*)d_in[12];
  const float* W2   = (const float*)d_in[13];
  const float* b2   = (const float*)d_in[14];
  const float* Wc1  = (const float*)d_in[15];
  const float* bc1  = (const float*)d_in[16];
  const float* Wc2  = (const float*)d_in[17];
  const float* bc2  = (const float*)d_in[18];

  const int B = in_sizes[1];  // 2048
  const size_t fragB = (size_t)100 * WSM * sizeof(unsigned short);
  const size_t need = fragB + (size_t)2 * B * sizeof(float);
  if (ws_size < need) return;

  unsigned short* wsb = (unsigned short*)d_ws;
  float* wsf = (float*)((char*)d_ws + fragB);
  float* out = (float*)d_out;

  prep_all<<<100, 256, 0, stream>>>(Wq, bq, Wk, bk, Wv, bv, Wh, bh, Wout,
                                    W1, b1, W2, b2, wsb);
  encoder_kernel<<<B, 64, 0, stream>>>(emb, labels, wsb, Wc1, bc1, Wc2, bc2,
                                       wsf, wsf + B);
  reduce_kernel<<<1, 256, 0, stream>>>(wsf, wsf + B, out, B);
}

// Round 15
// 148.671 us; speedup vs baseline: 2.0303x; 1.1437x over previous
//
#include <hip/hip_runtime.h>
#include <math.h>

namespace {

constexpr int D    = 49;
constexpr int H    = 8;
constexpr int L    = 4;
constexpr int HID  = 25;
constexpr int NCLS = 10;
constexpr int XS   = 68;    // LDS staging row stride (bf16 elems)
constexpr int WSM  = 4096;  // ushorts per padded 64x64 matrix in frag layout
// fold 1/(sqrt(49)+1e-6) * log2(e) into M so softmax uses exp2 directly
constexpr float SCLF  = 1.44269504088896f / (7.0f + 1e-6f);
constexpr float CLIP2 = 30.0f * 1.44269504088896f;  // clip bounds in log2 domain

typedef __attribute__((ext_vector_type(4))) short short4v;
typedef __attribute__((ext_vector_type(8))) short short8v;
typedef __attribute__((ext_vector_type(4))) float float4v;
typedef __attribute__((ext_vector_type(8))) __bf16 bf16x8;

__device__ __forceinline__ float4v mfma32(short8v a, short8v b, float4v c) {
  return __builtin_amdgcn_mfma_f32_16x16x32_bf16(a, b, c, 0, 0, 0);
}

__device__ __forceinline__ unsigned short f2bf(float x) {  // RNE
  unsigned u = __float_as_uint(x);
  return (unsigned short)((u + 0x7FFFu + ((u >> 16) & 1u)) >> 16);
}

__device__ __forceinline__ short8v cvt8(float4v lo, float4v hi) {
  bf16x8 b = {(__bf16)lo[0], (__bf16)lo[1], (__bf16)lo[2], (__bf16)lo[3],
              (__bf16)hi[0], (__bf16)hi[1], (__bf16)hi[2], (__bf16)hi[3]};
  return __builtin_bit_cast(short8v, b);
}

__device__ __forceinline__ float exp2_hw(float x) {  // x bounded by clip: safe
  float r;
  asm("v_exp_f32 %0, %1" : "=v"(r) : "v"(x));
  return r;
}

__device__ __forceinline__ float4v splat4(float x) {
  float4v v; v[0] = x; v[1] = x; v[2] = x; v[3] = x; return v;
}

__device__ __forceinline__ short8v wsld8(const unsigned short* __restrict__ w,
                                         int t, int nt, int lane) {
  return *reinterpret_cast<const short8v*>(w + ((t * 4 + nt) * 64 + lane) * 8);
}

// acc(cfrag of OUT^T) = W^T @ SRC   (all biases live inside W via ones-column)
__device__ __forceinline__ void mmT8(const unsigned short* __restrict__ w,
                                     const short8v (&src)[2][4],
                                     int lane, float4v (&acc)[4][4]) {
  #pragma unroll
  for (int mt = 0; mt < 4; ++mt)
    #pragma unroll
    for (int nt = 0; nt < 4; ++nt) acc[mt][nt] = splat4(0.0f);
  #pragma unroll
  for (int t = 0; t < 2; ++t) {
    short8v a[4];
    #pragma unroll
    for (int mt = 0; mt < 4; ++mt) a[mt] = wsld8(w, t, mt, lane);
    #pragma unroll
    for (int nt = 0; nt < 4; ++nt)
      #pragma unroll
      for (int mt = 0; mt < 4; ++mt)
        acc[mt][nt] = mfma32(a[mt], src[t][nt], acc[mt][nt]);
  }
}

// pack a padded 50x50 matrix (rows 0-48 in M, row 49 in row49[0..49],
// col 49 in col49[0..48] or zeros) into the 64x64 bf16 K=32 frag layout.
__device__ __forceinline__ void pack2(const float* __restrict__ M,
                                      const float* __restrict__ row49,
                                      const float* __restrict__ col49,
                                      unsigned short* __restrict__ dst, int tid) {
  const int lane = tid & 63;
  const int gg = (lane >> 4) & 3, cc = lane & 15;
  #pragma unroll
  for (int i = 0; i < 2; ++i) {
    const int p = ((tid >> 6) << 1) | i;  // 0..7
    const int tt = p >> 2, nt = p & 3;
    short8v v;
    #pragma unroll
    for (int j = 0; j < 8; ++j) {
      const int k = 32 * tt + ((j < 4) ? (4 * gg + j) : (16 + 4 * gg + j - 4));
      const int n = 16 * nt + cc;
      float f = 0.0f;
      if (k < D) {
        if (n < D)       f = M[k * D + n];
        else if (n == D) f = col49 ? col49[k] : 0.0f;
      } else if (k == D) {
        if (n <= D)      f = row49[n];
      }
      v[j] = (short)f2bf(f);
    }
    *reinterpret_cast<short8v*>(dst + ((tt * 4 + nt) * 64 + lane) * 8) = v;
  }
}

// 49x49 @ 49x49 in LDS -> LDS; k fully unrolled for ILP.
__device__ __forceinline__ void lds_mm(const float* __restrict__ A49,
                                       const float* __restrict__ B49,
                                       float* __restrict__ OUT, int tid) {
  for (int i = tid; i < D * D; i += 256) {
    const int r = i / D, c = i - r * D;
    float s = 0.0f;
    #pragma unroll
    for (int k = 0; k < D; ++k) s = fmaf(A49[r * D + k], B49[k * D + c], s);
    OUT[i] = s;
  }
}

// ---- single-launch prep: compose + pack 68 frag matrices ----
// block m: 0-31  M_h = Wk~ @ Wq~^T * SCLF  (50x50: biases in row/col 49,
//                corner = bk.bq; folds QK, both biases, scale, log2)
//          32-63 Wfull = Wv @ Wh @ Wout (+bv@Wh@Wout row, corner 1/8)
//          64-67 W12 = W1@W2 (+b1@W2+b2+(sum_h bh@Wout)@W12 row, corner 1)
__global__ void __launch_bounds__(256)
prep_all(const float* __restrict__ Wq, const float* __restrict__ bq,
         const float* __restrict__ Wk, const float* __restrict__ bk,
         const float* __restrict__ Wv, const float* __restrict__ bv,
         const float* __restrict__ Wh, const float* __restrict__ bh,
         const float* __restrict__ Wout,
         const float* __restrict__ W1, const float* __restrict__ b1,
         const float* __restrict__ W2, const float* __restrict__ b2,
         unsigned short* __restrict__ ws) {
  __shared__ float MA[D * D], MB[D * D], MT[D * D];
  __shared__ float BR[64], CL[64], VA[64], VB[64], BH[8 * 64];
  const int m = blockIdx.x;  // 0..67
  const int tid = threadIdx.x;
  unsigned short* dst = ws + (size_t)m * WSM;

  if (m < 32) {  // M_h: rows 0-48 = Wk@Wq^T, row49 = bk@Wq^T, col49 = Wk@bq
    const int lh = m;
    for (int i = tid; i < D * D; i += 256) {
      MA[i] = Wk[(size_t)lh * D * D + i];
      MB[i] = Wq[(size_t)lh * D * D + i];
    }
    if (tid < D) { VA[tid] = bk[lh * D + tid]; VB[tid] = bq[lh * D + tid]; }
    __syncthreads();
    for (int i = tid; i < D * D; i += 256) {  // M[r][c] = sum_e Wk[r][e]Wq[c][e]
      const int r = i / D, c = i - r * D;
      float s = 0.0f;
      #pragma unroll
      for (int e = 0; e < D; ++e) s = fmaf(MA[r * D + e], MB[c * D + e], s);
      MT[i] = s * SCLF;
    }
    if (tid < D) {
      float s = 0.0f, s2 = 0.0f;
      #pragma unroll
      for (int e = 0; e < D; ++e) {
        s  = fmaf(VA[e], MB[tid * D + e], s);   // row 49: bk @ Wq^T
        s2 = fmaf(MA[tid * D + e], VB[e], s2);  // col 49: Wk @ bq
      }
      BR[tid] = s * SCLF;
      CL[tid] = s2 * SCLF;
    }
    if (tid == 0) {
      float s = 0.0f;
      #pragma unroll
      for (int e = 0; e < D; ++e) s = fmaf(VA[e], VB[e], s);
      BR[D] = s * SCLF;  // corner bk.bq
    }
    __syncthreads();
    pack2(MT, BR, CL, dst, tid);
    return;
  }

  if (m < 64) {  // Wfull = Wv @ (Wh @ Wout), bias row = bv @ (Wh@Wout)
    const int lh = m - 32;
    const float* wh = Wh + (size_t)lh * D * D;
    const float* wo = Wout + (size_t)lh * D * D;
    const float* wv = Wv + (size_t)lh * D * D;
    for (int i = tid; i < D * D; i += 256) { MA[i] = wh[i]; MB[i] = wo[i]; }
    __syncthreads();
    lds_mm(MA, MB, MT, tid);  // MT = Wh @ Wout
    __syncthreads();
    for (int i = tid; i < D * D; i += 256) MA[i] = wv[i];
    if (tid < D) {
      float s = 0.0f;
      #pragma unroll
      for (int k = 0; k < D; ++k) s = fmaf(bv[lh * D + k], MT[k * D + tid], s);
      BR[tid] = s;
    }
    if (tid == 0) BR[D] = 0.125f;
    __syncthreads();
    lds_mm(MA, MT, MB, tid);  // MB = Wv @ MT
    __syncthreads();
    pack2(MB, BR, nullptr, dst, tid);
    return;
  }

  // W12 = W1 @ W2; bias row = b1@W2 + b2 + (sum_h bh@Wout)@W12
  const int l = m - 64;
  for (int i = tid; i < D * D; i += 256) {
    MA[i] = W1[(size_t)l * D * D + i];
    MB[i] = W2[(size_t)l * D * D + i];
  }
  for (int i = tid; i < H * D; i += 256)
    BH[(i / D) * 64 + (i % D)] = bh[(l * H + (i / D)) * D + (i % D)];
  __syncthreads();
  if (tid < D) {  // CL = sum_h bh_h @ Wout_h
    float s = 0.0f;
    #pragma unroll
    for (int h = 0; h < H; ++h) {
      const size_t base = (size_t)(l * H + h) * D * D;
      #pragma unroll
      for (int k = 0; k < D; ++k)
        s = fmaf(BH[h * 64 + k], Wout[base + k * D + tid], s);
    }
    CL[tid] = s;
  }
  __syncthreads();
  lds_mm(MA, MB, MT, tid);  // MT = W1 @ W2
  __syncthreads();
  if (tid < D) {
    float s = b2[l * D + tid];
    #pragma unroll
    for (int k = 0; k < D; ++k) {
      s = fmaf(b1[l * D + k], MB[k * D + tid], s);
      s = fmaf(CL[k], MT[k * D + tid], s);
    }
    BR[tid] = s;
  }
  if (tid == 0) BR[D] = 1.0f;
  __syncthreads();
  pack2(MT, BR, nullptr, dst, tid);
}

__global__ void __launch_bounds__(64, 2)
encoder_kernel(const float* __restrict__ emb, const int* __restrict__ labels,
               const unsigned short* __restrict__ ws,
               const float* __restrict__ Wc1, const float* __restrict__ bc1,
               const float* __restrict__ Wc2, const float* __restrict__ bc2,
               float* __restrict__ ws_loss, float* __restrict__ ws_corr) {
  __shared__ unsigned short X[64 * XS];  // embedding staging only
  __shared__ float CLS[128];

  const int b = blockIdx.x;
  const int lane = threadIdx.x;          // one wave per block
  const int g = lane >> 4, c = lane & 15;

  // ---- stage embedding (64x64 bf16; col 49 = ones-column, rest pad 0) ----
  for (int idx = lane; idx < 64 * 64; idx += 64) {
    const int r = idx >> 6, cc = idx & 63;
    float v = 0.0f;
    if (cc == D) v = 1.0f;
    else if (r < D && cc < D) v = emb[(size_t)b * (D * D) + r * D + cc];
    X[r * XS + cc] = f2bf(v);
  }
  __syncthreads();

  short8v xf8[2][4];  // operand frag of X~ (contraction over d)
  #pragma unroll
  for (int t = 0; t < 2; ++t)
    #pragma unroll
    for (int nt = 0; nt < 4; ++nt) {
      const int base = (16 * nt + c) * XS + 32 * t + 4 * g;
      short4v lo = *reinterpret_cast<const short4v*>(&X[base]);
      short4v hi = *reinterpret_cast<const short4v*>(&X[base + 16]);
      xf8[t][nt] = __builtin_shufflevector(lo, hi, 0, 1, 2, 3, 4, 5, 6, 7);
    }

  float4v xacc[4][4];  // cfrag(x^T)

  #pragma unroll 1
  for (int l = 0; l < L; ++l) {
    float4v od[4][4];  // cfrag(od^T) f32 accumulator across heads
    #pragma unroll
    for (int mt = 0; mt < 4; ++mt)
      #pragma unroll
      for (int nt = 0; nt < 4; ++nt) od[mt][nt] = splat4(0.0f);

    // unroll 2: consecutive heads are independent until the od accumulate.
    #pragma unroll 2
    for (int h = 0; h < H; ++h) {
      const int lh = l * H + h;
      const unsigned short* wm = ws + (size_t)lh * WSM;         // M_h
      const unsigned short* wf = ws + (size_t)(32 + lh) * WSM;  // Wfull

      // ---- T^T = M^T-contract X: S^T = T @ X~^T later uses xf8 as B ----
      short8v tf8[2][4];
      {
        float4v ta[4][4];
        mmT8(wm, xf8, lane, ta);
        #pragma unroll
        for (int t = 0; t < 2; ++t)
          #pragma unroll
          for (int nt = 0; nt < 4; ++nt)
            tf8[t][nt] = cvt8(ta[2 * t][nt], ta[2 * t + 1][nt]);
      }

      // ---- U = X~ @ Wfull' (rows = patch, cols = o; col 49 = 1/8) ----
      short8v uf8[2][4];
      {
        float4v ua[4][4];
        #pragma unroll
        for (int nt = 0; nt < 4; ++nt)
          #pragma unroll
          for (int mt = 0; mt < 4; ++mt) ua[mt][nt] = splat4(0.0f);
        #pragma unroll
        for (int t = 0; t < 2; ++t) {
          short8v wff[4];
          #pragma unroll
          for (int nt = 0; nt < 4; ++nt) wff[nt] = wsld8(wf, t, nt, lane);
          #pragma unroll
          for (int nt = 0; nt < 4; ++nt)
            #pragma unroll
            for (int mt = 0; mt < 4; ++mt)
              ua[mt][nt] = mfma32(xf8[t][mt], wff[nt], ua[mt][nt]);
        }
        #pragma unroll
        for (int t = 0; t < 2; ++t)
          #pragma unroll
          for (int nt = 0; nt < 4; ++nt)
            uf8[t][nt] = cvt8(ua[2 * t][nt], ua[2 * t + 1][nt]);
      }

      // ---- per query tile nt: S col -> softmax -> PU -> od ----
      #pragma unroll
      for (int nt = 0; nt < 4; ++nt) {
        float4v sc[4];
        #pragma unroll
        for (int mt = 0; mt < 4; ++mt) sc[mt] = splat4(0.0f);
        #pragma unroll
        for (int t = 0; t < 2; ++t)
          #pragma unroll
          for (int mt = 0; mt < 4; ++mt)
            sc[mt] = mfma32(tf8[t][mt], xf8[t][nt], sc[mt]);

        // max-free softmax (log2 domain); compile-time pad mask:
        // key j = 16mt+4g+r: mt==3,r>0 always pad; mt==3,r==0 needs g==0.
        #pragma unroll
        for (int mt = 0; mt < 4; ++mt)
          #pragma unroll
          for (int r = 0; r < 4; ++r) {
            if (mt == 3 && r > 0) { sc[mt][r] = 0.0f; continue; }
            const float sv = fminf(fmaxf(sc[mt][r], -CLIP2), CLIP2);
            float p = exp2_hw(sv);
            if (mt == 3) p = (g == 0) ? p : 0.0f;
            sc[mt][r] = p;
          }
        const short8v pf0 = cvt8(sc[0], sc[1]);
        const short8v pf1 = cvt8(sc[2], sc[3]);

        float4v cc[4];
        #pragma unroll
        for (int mt = 0; mt < 4; ++mt) cc[mt] = splat4(0.0f);
        #pragma unroll
        for (int mt = 0; mt < 4; ++mt) {
          cc[mt] = mfma32(uf8[0][mt], pf0, cc[mt]);
          cc[mt] = mfma32(uf8[1][mt], pf1, cc[mt]);
        }
        // row 49 = (mt=3, g=0, reg r=1) holds den/8; lane c reads col q=16nt+c
        const float inv = 0.125f / __shfl(cc[3][1], c);
        const float4v iv = splat4(inv);
        #pragma unroll
        for (int mt = 0; mt < 4; ++mt)
          od[mt][nt] += cc[mt] * iv;
      }
    }  // heads

    // ---- fused MLP: x^T = W12'^T @ od^T (bias+head-bias in row 49) ----
    short8v of8[2][4];
    #pragma unroll
    for (int t = 0; t < 2; ++t)
      #pragma unroll
      for (int nt = 0; nt < 4; ++nt)
        of8[t][nt] = cvt8(od[2 * t][nt], od[2 * t + 1][nt]);
    mmT8(ws + (size_t)(64 + l) * WSM, of8, lane, xacc);

    if (l < L - 1) {
      #pragma unroll
      for (int t = 0; t < 2; ++t)
        #pragma unroll
        for (int nt = 0; nt < 4; ++nt)
          xf8[t][nt] = cvt8(xacc[2 * t][nt], xacc[2 * t + 1][nt]);
    }
  }  // layers

  // ---- pooled[d] = mean over patch cols < 49 of x^T ----
  #pragma unroll
  for (int mt = 0; mt < 4; ++mt) {
    #pragma unroll
    for (int r = 0; r < 4; ++r) {
      float sv = xacc[mt][0][r] + xacc[mt][1][r] + xacc[mt][2][r];
      if (c == 0) sv += xacc[mt][3][r];  // patch 48; 49..63 pad
      sv += __shfl_xor(sv, 1);
      sv += __shfl_xor(sv, 2);
      sv += __shfl_xor(sv, 4);
      sv += __shfl_xor(sv, 8);
      if (c == 0) CLS[16 * mt + 4 * g + r] = sv * (1.0f / 49.0f);
    }
  }
  __syncthreads();

  // ---- classifier head (f32 scalar path) ----
  if (lane < HID) {
    float acc = bc1[lane];
    #pragma unroll
    for (int d = 0; d < D; ++d) acc = fmaf(CLS[d], Wc1[d * HID + lane], acc);
    CLS[64 + lane] = acc;
  }
  __syncthreads();
  if (lane < NCLS) {
    float acc = bc2[lane];
    #pragma unroll
    for (int j = 0; j < HID; ++j) acc = fmaf(CLS[64 + j], Wc2[j * NCLS + lane], acc);
    CLS[96 + lane] = acc;
  }
  __syncthreads();
  if (lane == 0) {
    float mx = CLS[96];
    int am = 0;
    #pragma unroll 1
    for (int cc2 = 1; cc2 < NCLS; ++cc2) {
      const float v = CLS[96 + cc2];
      if (v > mx) { mx = v; am = cc2; }  // strict '>' == first max (jnp.argmax)
    }
    float se = 0.0f;
    #pragma unroll 1
    for (int cc2 = 0; cc2 < NCLS; ++cc2) se += expf(CLS[96 + cc2] - mx);
    const float lse = mx + logf(se);
    const int lbl = labels[b];
    ws_loss[b] = lse - CLS[96 + lbl];
    ws_corr[b] = (am == lbl) ? 1.0f : 0.0f;
  }
}

__global__ void __launch_bounds__(256)
reduce_kernel(const float* __restrict__ wsl, const float* __restrict__ wsc,
              float* __restrict__ out, int n) {
  __shared__ float sl[256];
  __shared__ float sc[256];
  const int t = threadIdx.x;
  float a = 0.0f, cc = 0.0f;
  for (int idx = t; idx < n; idx += 256) { a += wsl[idx]; cc += wsc[idx]; }
  sl[t] = a; sc[t] = cc;
  __syncthreads();
  for (int s = 128; s > 0; s >>= 1) {
    if (t < s) { sl[t] += sl[t + s]; sc[t] += sc[t + s]; }
    __syncthreads();
  }
  if (t == 0) {
    out[0] = sl[0] / (float)n;
    out[1] = sc[0] / (float)n;
  }
}

}  // namespace

extern "C" void kernel_launch(void* const* d_in, const int* in_sizes, int n_in,
                              void* d_out, int out_size, void* d_ws, size_t ws_size,
                              hipStream_t stream) {
  const float* emb    = (const float*)d_in[0];
  const int*   labels = (const int*)d_in[1];
  const float* Wq   = (const float*)d_in[2];
  const float* bq   = (const float*)d_in[3];
  const float* Wk   = (const float*)d_in[4];
  const float* bk   = (const float*)d_in[5];
  const float* Wv   = (const float*)d_in[6];
  const float* bv   = (const float*)d_in[7];
  const float* Wh   = (const float*)d_in[8];
  const float* bh   = (const float*)d_in[9];
  const float* Wout = (const float*)d_in[10];
  const float* W1   = (const float*)d_in[11];
  const float* b1   = (const float*)d_in[12];
  const float* W2   = (const float*)d_in[13];
  const float* b2   = (const float*)d_in[14];
  const float* Wc1  = (const float*)d_in[15];
  const float* bc1  = (const float*)d_in[16];
  const float* Wc2  = (const float*)d_in[17];
  const float* bc2  = (const float*)d_in[18];

  const int B = in_sizes[1];  // 2048
  const size_t fragB = (size_t)68 * WSM * sizeof(unsigned short);
  const size_t need = fragB + (size_t)2 * B * sizeof(float);
  if (ws_size < need) return;

  unsigned short* wsb = (unsigned short*)d_ws;
  float* wsf = (float*)((char*)d_ws + fragB);
  float* out = (float*)d_out;

  prep_all<<<68, 256, 0, stream>>>(Wq, bq, Wk, bk, Wv, bv, Wh, bh, Wout,
                                   W1, b1, W2, b2, wsb);
  encoder_kernel<<<B, 64, 0, stream>>>(emb, labels, wsb, Wc1, bc1, Wc2, bc2,
                                       wsf, wsf + B);
  reduce_kernel<<<1, 256, 0, stream>>>(wsf, wsf + B, out, B);
}